// Round 2
// baseline (575.709 us; speedup 1.0000x reference)
//
#include <hip/hip_runtime.h>

// Winograd F(2x2,3x3): x (8,64,128,128) f32, filt (64,64,3,3) f32 -> Y (8,64,126,126) f32
// T = 63 tiles per dim. U = G g G^T stored transposed [c][k][4][4] in d_ws (256 KB).

#define N_B 8
#define C_CH 64
#define K_CH 64
#define T_TILES 63
#define HW 128
#define OW 126
#define CCHUNK 32

__global__ __launch_bounds__(256)
void filter_transform(const float* __restrict__ g, float* __restrict__ U) {
    int idx = blockIdx.x * 256 + threadIdx.x;   // k*64 + c
    if (idx >= K_CH * C_CH) return;
    int k = idx >> 6;
    int c = idx & 63;
    const float* gp = g + idx * 9;
    float g00 = gp[0], g01 = gp[1], g02 = gp[2];
    float g10 = gp[3], g11 = gp[4], g12 = gp[5];
    float g20 = gp[6], g21 = gp[7], g22 = gp[8];
    float w[4][3];
    w[0][0] = g00;                     w[0][1] = g01;                     w[0][2] = g02;
    w[1][0] = 0.5f*(g00+g10+g20);      w[1][1] = 0.5f*(g01+g11+g21);      w[1][2] = 0.5f*(g02+g12+g22);
    w[2][0] = 0.5f*(g00-g10+g20);      w[2][1] = 0.5f*(g01-g11+g21);      w[2][2] = 0.5f*(g02-g12+g22);
    w[3][0] = g20;                     w[3][1] = g21;                     w[3][2] = g22;
    float* up = U + ((size_t)(c * K_CH + k)) * 16;   // transposed layout [c][k][ab]
    #pragma unroll
    for (int a = 0; a < 4; ++a) {
        up[a*4+0] = w[a][0];
        up[a*4+1] = 0.5f*(w[a][0] + w[a][1] + w[a][2]);
        up[a*4+2] = 0.5f*(w[a][0] - w[a][1] + w[a][2]);
        up[a*4+3] = w[a][2];
    }
}

// Each block: one n, one 4x4 patch of tiles (16 tiles). 256 threads.
// LDS: V[cl=32][tile=16] stride 20 floats (16B aligned, 2-way bank alias = free). 40 KB.
__global__ __launch_bounds__(256, 4)
void winograd_main(const float* __restrict__ x, const float* __restrict__ U,
                   float* __restrict__ Y) {
    __shared__ float Vs[CCHUNK * 16 * 20];   // 40 KB -> 4 blocks/CU

    const int tid = threadIdx.x;
    const int n  = blockIdx.y;
    const int pt = blockIdx.x >> 4;
    const int pu = blockIdx.x & 15;

    // Phase-2 thread mapping: k = tid>>2 (one k per thread), tg = tid&3 (tile column)
    const int k  = tid >> 2;
    const int tg = tid & 3;

    float4 acc[4][4];   // [tile row j][ab row q]
    #pragma unroll
    for (int j = 0; j < 4; ++j)
        #pragma unroll
        for (int q = 0; q < 4; ++q)
            acc[j][q] = make_float4(0.f, 0.f, 0.f, 0.f);

    for (int cc0 = 0; cc0 < C_CH; cc0 += CCHUNK) {
        // ---- Phase 1: input transform for this c-chunk into LDS ----
        #pragma unroll
        for (int i = 0; i < 2; ++i) {
            int idx  = tid + 256 * i;        // 0..511
            int cl   = idx >> 4;             // 0..31
            int tile = idx & 15;
            int c    = cc0 + cl;
            int tt = pt * 4 + (tile >> 2);
            int uu = pu * 4 + (tile & 3);
            float* vp = &Vs[(cl * 16 + tile) * 20];
            if (tt < T_TILES && uu < T_TILES) {
                const float* xp = x + (((size_t)(n * C_CH + c) * HW) + 2 * tt) * HW + 2 * uu;
                float d[4][4];
                #pragma unroll
                for (int r = 0; r < 4; ++r) {
                    float2 lo = *reinterpret_cast<const float2*>(xp + r * HW);
                    float2 hi = *reinterpret_cast<const float2*>(xp + r * HW + 2);
                    d[r][0] = lo.x; d[r][1] = lo.y; d[r][2] = hi.x; d[r][3] = hi.y;
                }
                float w[4][4];
                #pragma unroll
                for (int jj = 0; jj < 4; ++jj) {
                    w[0][jj] = d[0][jj] - d[2][jj];
                    w[1][jj] = d[1][jj] + d[2][jj];
                    w[2][jj] = d[2][jj] - d[1][jj];
                    w[3][jj] = d[1][jj] - d[3][jj];
                }
                #pragma unroll
                for (int a = 0; a < 4; ++a) {
                    vp[a*4+0] = w[a][0] - w[a][2];
                    vp[a*4+1] = w[a][1] + w[a][2];
                    vp[a*4+2] = w[a][2] - w[a][1];
                    vp[a*4+3] = w[a][1] - w[a][3];
                }
            } else {
                #pragma unroll
                for (int a = 0; a < 16; ++a) vp[a] = 0.0f;
            }
        }
        __syncthreads();

        // ---- Phase 2: M[k,tile,a,b] += sum_{c in chunk} U[c,k,a,b] * V[c,tile,a,b] ----
        #pragma unroll 2
        for (int cl = 0; cl < CCHUNK; ++cl) {
            const float4* up = reinterpret_cast<const float4*>(
                U + ((size_t)((cc0 + cl) * K_CH + k)) * 16);
            float4 u0 = up[0], u1 = up[1], u2 = up[2], u3 = up[3];
            #pragma unroll
            for (int j = 0; j < 4; ++j) {
                const float* vp = &Vs[(cl * 16 + (j * 4 + tg)) * 20];
                float4 v0 = *reinterpret_cast<const float4*>(vp + 0);
                float4 v1 = *reinterpret_cast<const float4*>(vp + 4);
                float4 v2 = *reinterpret_cast<const float4*>(vp + 8);
                float4 v3 = *reinterpret_cast<const float4*>(vp + 12);
                acc[j][0].x += u0.x * v0.x; acc[j][0].y += u0.y * v0.y;
                acc[j][0].z += u0.z * v0.z; acc[j][0].w += u0.w * v0.w;
                acc[j][1].x += u1.x * v1.x; acc[j][1].y += u1.y * v1.y;
                acc[j][1].z += u1.z * v1.z; acc[j][1].w += u1.w * v1.w;
                acc[j][2].x += u2.x * v2.x; acc[j][2].y += u2.y * v2.y;
                acc[j][2].z += u2.z * v2.z; acc[j][2].w += u2.w * v2.w;
                acc[j][3].x += u3.x * v3.x; acc[j][3].y += u3.y * v3.y;
                acc[j][3].z += u3.z * v3.z; acc[j][3].w += u3.w * v3.w;
            }
        }
        __syncthreads();
    }

    // ---- Phase 3: output transform Yt = AT * M * AT^T, store 2x2 per tile ----
    #pragma unroll
    for (int j = 0; j < 4; ++j) {
        const int tt = pt * 4 + j;
        const int uu = pu * 4 + tg;
        if (tt < T_TILES && uu < T_TILES) {
            float4 m0 = acc[j][0], m1 = acc[j][1], m2 = acc[j][2], m3 = acc[j][3];
            float w00 = m0.x + m1.x + m2.x;
            float w01 = m0.y + m1.y + m2.y;
            float w02 = m0.z + m1.z + m2.z;
            float w03 = m0.w + m1.w + m2.w;
            float w10 = m1.x - m2.x - m3.x;
            float w11 = m1.y - m2.y - m3.y;
            float w12 = m1.z - m2.z - m3.z;
            float w13 = m1.w - m2.w - m3.w;
            float y00 = w00 + w01 + w02;
            float y01 = w01 - w02 - w03;
            float y10 = w10 + w11 + w12;
            float y11 = w11 - w12 - w13;
            float* yp = Y + (((size_t)(n * K_CH + k) * OW) + 2 * tt) * OW + 2 * uu;
            *reinterpret_cast<float2*>(yp)      = make_float2(y00, y01);
            *reinterpret_cast<float2*>(yp + OW) = make_float2(y10, y11);
        }
    }
}

extern "C" void kernel_launch(void* const* d_in, const int* in_sizes, int n_in,
                              void* d_out, int out_size, void* d_ws, size_t ws_size,
                              hipStream_t stream) {
    const float* x    = (const float*)d_in[0];
    const float* filt = (const float*)d_in[1];
    float* Y = (float*)d_out;
    float* U = (float*)d_ws;   // 64*64*16 floats = 256 KB, layout [c][k][4][4]

    filter_transform<<<16, 256, 0, stream>>>(filt, U);

    dim3 grid(256, N_B);   // 16x16 patches, 8 batches
    winograd_main<<<grid, 256, 0, stream>>>(x, U, Y);
}

// Round 3
// 139.369 us; speedup vs baseline: 4.1308x; 4.1308x over previous
//
#include <hip/hip_runtime.h>

// Winograd F(2x2,3x3) via bf16 MFMA.
// x (8,64,128,128) f32, filt (64,64,3,3) f32 -> Y (8,64,126,126) f32
// Per block: one (n, 4x4 tile patch). 16 ab-wise GEMMs [16 tiles x 64c] x [64c x 64k].

#define N_B 8
#define T_TILES 63
#define HW 128
#define OW 126

typedef __attribute__((ext_vector_type(8))) short short8;   // 8 bf16 = 4 VGPR
typedef __attribute__((ext_vector_type(4))) float f32x4;

static __device__ __forceinline__ unsigned int f2bf(float f) {
    unsigned int u = __float_as_uint(f);
    return (u + 0x7FFFu + ((u >> 16) & 1u)) >> 16;   // RNE bf16 (finite inputs)
}

// U_frag layout: frag[(ab*2+ck)*4+kq][lane 0..63][j 0..7] bf16  (128 KB total)
// B-operand of mfma_f32_16x16x32_bf16: lane l holds B[c=(l>>4)*8+j + 32*ck][k=(l&15)+16*kq]
__global__ __launch_bounds__(256)
void filter_transform(const float* __restrict__ g, unsigned short* __restrict__ Uf) {
    int idx = blockIdx.x * 256 + threadIdx.x;   // k*64 + c
    if (idx >= 64 * 64) return;
    int k = idx >> 6, c = idx & 63;
    const float* gp = g + idx * 9;
    float g00 = gp[0], g01 = gp[1], g02 = gp[2];
    float g10 = gp[3], g11 = gp[4], g12 = gp[5];
    float g20 = gp[6], g21 = gp[7], g22 = gp[8];
    float w[4][3];
    w[0][0] = g00;                w[0][1] = g01;                w[0][2] = g02;
    w[1][0] = 0.5f*(g00+g10+g20); w[1][1] = 0.5f*(g01+g11+g21); w[1][2] = 0.5f*(g02+g12+g22);
    w[2][0] = 0.5f*(g00-g10+g20); w[2][1] = 0.5f*(g01-g11+g21); w[2][2] = 0.5f*(g02-g12+g22);
    w[3][0] = g20;                w[3][1] = g21;                w[3][2] = g22;

    int kq = k >> 4, kl = k & 15;
    int ck = c >> 5;
    int lane = kl + (((c & 31) >> 3) << 4);
    int j = c & 7;
    #pragma unroll
    for (int a = 0; a < 4; ++a) {
        float u0 = w[a][0];
        float u1 = 0.5f * (w[a][0] + w[a][1] + w[a][2]);
        float u2 = 0.5f * (w[a][0] - w[a][1] + w[a][2]);
        float u3 = w[a][2];
        float uv[4] = {u0, u1, u2, u3};
        #pragma unroll
        for (int b = 0; b < 4; ++b) {
            int ab = a * 4 + b;
            size_t off = ((size_t)((ab * 2 + ck) * 4 + kq) * 64 + lane) * 8 + j;
            Uf[off] = (unsigned short)f2bf(uv[b]);
        }
    }
}

// 256 threads = 4 waves; wave w handles k-quarter kq=w for ALL 16 ab.
// LDS: V bf16 [ab 16][tile 16][c 64], 32 KB, byte ^= ((tile&7)<<4) swizzle.
__global__ __launch_bounds__(256)
void winograd_main(const float* __restrict__ x, const unsigned short* __restrict__ Uf,
                   float* __restrict__ Y) {
    __shared__ uint4 Vs4[2048];                     // 32 KB
    char* Vs = (char*)Vs4;

    const int tid  = threadIdx.x;
    const int lane = tid & 63;
    const int wv   = tid >> 6;                     // wave id = kq
    const int n  = blockIdx.y;
    const int pt = blockIdx.x >> 4;
    const int pu = blockIdx.x & 15;

    // ---- Phase 1: input transform -> bf16 V in LDS (2 channels per thread-iter) ----
    #pragma unroll
    for (int it = 0; it < 2; ++it) {
        int idx  = tid + 256 * it;                 // 0..511
        int cp   = idx >> 4;                       // 0..31 -> channels 2cp, 2cp+1
        int tile = idx & 15;
        int c0   = cp * 2;
        int tt = pt * 4 + (tile >> 2);
        int uu = pu * 4 + (tile & 3);
        unsigned int vpack[16];
        if (tt < T_TILES && uu < T_TILES) {
            float vv[2][16];
            #pragma unroll
            for (int h = 0; h < 2; ++h) {
                const float* xp = x + (((size_t)(n * 64 + c0 + h) * HW) + 2 * tt) * HW + 2 * uu;
                float d[4][4];
                #pragma unroll
                for (int r = 0; r < 4; ++r) {
                    float2 lo = *reinterpret_cast<const float2*>(xp + r * HW);
                    float2 hi = *reinterpret_cast<const float2*>(xp + r * HW + 2);
                    d[r][0] = lo.x; d[r][1] = lo.y; d[r][2] = hi.x; d[r][3] = hi.y;
                }
                float wr[4][4];
                #pragma unroll
                for (int jj = 0; jj < 4; ++jj) {
                    wr[0][jj] = d[0][jj] - d[2][jj];
                    wr[1][jj] = d[1][jj] + d[2][jj];
                    wr[2][jj] = d[2][jj] - d[1][jj];
                    wr[3][jj] = d[1][jj] - d[3][jj];
                }
                #pragma unroll
                for (int a = 0; a < 4; ++a) {
                    vv[h][a*4+0] = wr[a][0] - wr[a][2];
                    vv[h][a*4+1] = wr[a][1] + wr[a][2];
                    vv[h][a*4+2] = wr[a][2] - wr[a][1];
                    vv[h][a*4+3] = wr[a][1] - wr[a][3];
                }
            }
            #pragma unroll
            for (int e = 0; e < 16; ++e)
                vpack[e] = f2bf(vv[0][e]) | (f2bf(vv[1][e]) << 16);
        } else {
            #pragma unroll
            for (int e = 0; e < 16; ++e) vpack[e] = 0u;
        }
        const int swz = (tile & 7) << 4;
        #pragma unroll
        for (int ab = 0; ab < 16; ++ab) {
            int byte = (ab * 2048 + tile * 128 + c0 * 2) ^ swz;
            *reinterpret_cast<unsigned int*>(Vs + byte) = vpack[ab];
        }
    }
    __syncthreads();

    // ---- Phase 2: 16 ab-GEMMs. A = V[tile][c] (LDS), B = U frags (global, L2-resident) ----
    f32x4 acc[16];
    #pragma unroll
    for (int ab = 0; ab < 16; ++ab) acc[ab] = (f32x4){0.f, 0.f, 0.f, 0.f};

    const int arow = lane & 15;                    // tile (M row)
    const int agrp = lane >> 4;                    // K group
    const int aswz = (arow & 7) << 4;
    const short8* UfV = reinterpret_cast<const short8*>(Uf);

    #pragma unroll 4
    for (int ab = 0; ab < 16; ++ab) {
        int base = ab * 2048 + arow * 128 + agrp * 16;
        short8 A0 = *reinterpret_cast<const short8*>(Vs + ((base)      ^ aswz));
        short8 A1 = *reinterpret_cast<const short8*>(Vs + ((base + 64) ^ aswz));
        short8 B0 = UfV[((ab * 2 + 0) * 4 + wv) * 64 + lane];
        short8 B1 = UfV[((ab * 2 + 1) * 4 + wv) * 64 + lane];
        acc[ab] = __builtin_amdgcn_mfma_f32_16x16x32_bf16(A0, B0, acc[ab], 0, 0, 0);
        acc[ab] = __builtin_amdgcn_mfma_f32_16x16x32_bf16(A1, B1, acc[ab], 0, 0, 0);
    }

    // ---- Phase 3: per-lane output transform + store (no LDS round-trip) ----
    // D[row=tile=(lane>>4)*4+r][col=k=(lane&15)], tile = 4*g + r -> tt_loc=g, uu_loc=r
    const int k  = (lane & 15) + wv * 16;
    const int gg = lane >> 4;
    const int tt = pt * 4 + gg;
    #pragma unroll
    for (int r = 0; r < 4; ++r) {
        const int uu = pu * 4 + r;
        if (tt < T_TILES && uu < T_TILES) {
            float m[16];
            #pragma unroll
            for (int ab = 0; ab < 16; ++ab) m[ab] = acc[ab][r];
            float w0[4], w1[4];
            #pragma unroll
            for (int b = 0; b < 4; ++b) {
                w0[b] = m[0 + b] + m[4 + b] + m[8 + b];
                w1[b] = m[4 + b] - m[8 + b] - m[12 + b];
            }
            float y00 = w0[0] + w0[1] + w0[2];
            float y01 = w0[1] - w0[2] - w0[3];
            float y10 = w1[0] + w1[1] + w1[2];
            float y11 = w1[1] - w1[2] - w1[3];
            float* yp = Y + (((size_t)(n * 64 + k)) * OW + 2 * tt) * OW + 2 * uu;
            *reinterpret_cast<float2*>(yp)      = make_float2(y00, y01);
            *reinterpret_cast<float2*>(yp + OW) = make_float2(y10, y11);
        }
    }
}

extern "C" void kernel_launch(void* const* d_in, const int* in_sizes, int n_in,
                              void* d_out, int out_size, void* d_ws, size_t ws_size,
                              hipStream_t stream) {
    const float* x    = (const float*)d_in[0];
    const float* filt = (const float*)d_in[1];
    float* Y = (float*)d_out;
    unsigned short* Uf = (unsigned short*)d_ws;    // 128 KB bf16 U fragments

    filter_transform<<<16, 256, 0, stream>>>(filt, Uf);

    dim3 grid(256, N_B);
    winograd_main<<<grid, 256, 0, stream>>>(x, Uf, Y);
}

// Round 4
// 104.624 us; speedup vs baseline: 5.5026x; 1.3321x over previous
//
#include <hip/hip_runtime.h>

// Winograd F(2x2,3x3) via bf16 MFMA, coalesced output staging.
// x (8,64,128,128) f32, filt (64,64,3,3) f32 -> Y (8,64,126,126) f32
// Block = (n, 2 tt-rows x 16 uu-tiles) = 32 tiles. 512 threads = 8 waves.

#define T_TILES 63
#define HW 128
#define OW 126

typedef __attribute__((ext_vector_type(8))) short short8;   // 8 bf16
typedef __attribute__((ext_vector_type(4))) float f32x4;

static __device__ __forceinline__ unsigned int f2bf(float f) {
    unsigned int u = __float_as_uint(f);
    return (u + 0x7FFFu + ((u >> 16) & 1u)) >> 16;   // RNE bf16
}

// U_frag layout: frag[(ab*2+ck)*4+kq][lane 0..63][j 0..7] bf16  (128 KB total)
// B-operand lane l holds B[c=(l>>4)*8+j+32*ck][k=(l&15)+16*kq]
__global__ __launch_bounds__(256)
void filter_transform(const float* __restrict__ g, unsigned short* __restrict__ Uf) {
    int idx = blockIdx.x * 256 + threadIdx.x;   // k*64 + c
    if (idx >= 64 * 64) return;
    int k = idx >> 6, c = idx & 63;
    const float* gp = g + idx * 9;
    float g00 = gp[0], g01 = gp[1], g02 = gp[2];
    float g10 = gp[3], g11 = gp[4], g12 = gp[5];
    float g20 = gp[6], g21 = gp[7], g22 = gp[8];
    float w[4][3];
    w[0][0] = g00;                w[0][1] = g01;                w[0][2] = g02;
    w[1][0] = 0.5f*(g00+g10+g20); w[1][1] = 0.5f*(g01+g11+g21); w[1][2] = 0.5f*(g02+g12+g22);
    w[2][0] = 0.5f*(g00-g10+g20); w[2][1] = 0.5f*(g01-g11+g21); w[2][2] = 0.5f*(g02-g12+g22);
    w[3][0] = g20;                w[3][1] = g21;                w[3][2] = g22;

    int kq = k >> 4, kl = k & 15;
    int ck = c >> 5;
    int lane = kl + (((c & 31) >> 3) << 4);
    int j = c & 7;
    #pragma unroll
    for (int a = 0; a < 4; ++a) {
        float uv[4];
        uv[0] = w[a][0];
        uv[1] = 0.5f * (w[a][0] + w[a][1] + w[a][2]);
        uv[2] = 0.5f * (w[a][0] - w[a][1] + w[a][2]);
        uv[3] = w[a][2];
        #pragma unroll
        for (int b = 0; b < 4; ++b) {
            int ab = a * 4 + b;
            size_t off = ((size_t)((ab * 2 + ck) * 4 + kq) * 64 + lane) * 8 + j;
            Uf[off] = (unsigned short)f2bf(uv[b]);
        }
    }
}

// V LDS: bf16 [ab 16][tile 32][c 64], byte = ab*4096 + ((tm*128 + c*2) ^ ((tm&7)<<4)). 64 KB.
// After GEMM, LDS reused for f32 Ys[k][r 0..3][col 0..31], idx = k*138 + r*34 + col.
__global__ __launch_bounds__(512)
void winograd_main(const float* __restrict__ x, const unsigned short* __restrict__ Uf,
                   float* __restrict__ Y) {
    __shared__ __align__(16) char smem[65536];

    const int tid  = threadIdx.x;
    const int lane = tid & 63;
    const int wv   = tid >> 6;       // 0..7
    const int mt   = wv >> 2;        // M-tile (tt_loc)
    const int kq   = wv & 3;         // k quarter
    const int n    = blockIdx.y;
    const int uub  = blockIdx.x & 3;
    const int ttb  = blockIdx.x >> 2;

    // ---- Phase 1: input transform -> bf16 V in LDS ----
    #pragma unroll
    for (int it = 0; it < 2; ++it) {
        int u    = tid + 512 * it;           // 0..1023
        int tm   = u & 31;                   // tile: tt_loc = tm>>4, uu_loc = tm&15
        int cp   = u >> 5;                   // 0..31 -> channels 2cp, 2cp+1
        int c0   = cp * 2;
        int tt = ttb * 2 + (tm >> 4);
        int uu = uub * 16 + (tm & 15);
        unsigned int vpack[16];
        if (tt < T_TILES && uu < T_TILES) {
            float vv[2][16];
            #pragma unroll
            for (int h = 0; h < 2; ++h) {
                const float* xp = x + (((size_t)(n * 64 + c0 + h) * HW) + 2 * tt) * HW + 2 * uu;
                float d[4][4];
                #pragma unroll
                for (int r = 0; r < 4; ++r) {
                    float2 lo = *reinterpret_cast<const float2*>(xp + r * HW);
                    float2 hi = *reinterpret_cast<const float2*>(xp + r * HW + 2);
                    d[r][0] = lo.x; d[r][1] = lo.y; d[r][2] = hi.x; d[r][3] = hi.y;
                }
                float wr[4][4];
                #pragma unroll
                for (int jj = 0; jj < 4; ++jj) {
                    wr[0][jj] = d[0][jj] - d[2][jj];
                    wr[1][jj] = d[1][jj] + d[2][jj];
                    wr[2][jj] = d[2][jj] - d[1][jj];
                    wr[3][jj] = d[1][jj] - d[3][jj];
                }
                #pragma unroll
                for (int a = 0; a < 4; ++a) {
                    vv[h][a*4+0] = wr[a][0] - wr[a][2];
                    vv[h][a*4+1] = wr[a][1] + wr[a][2];
                    vv[h][a*4+2] = wr[a][2] - wr[a][1];
                    vv[h][a*4+3] = wr[a][1] - wr[a][3];
                }
            }
            #pragma unroll
            for (int e = 0; e < 16; ++e)
                vpack[e] = f2bf(vv[0][e]) | (f2bf(vv[1][e]) << 16);
        } else {
            #pragma unroll
            for (int e = 0; e < 16; ++e) vpack[e] = 0u;
        }
        const int rowbase = (tm * 128 + c0 * 2) ^ ((tm & 7) << 4);
        #pragma unroll
        for (int ab = 0; ab < 16; ++ab)
            *reinterpret_cast<unsigned int*>(smem + ab * 4096 + rowbase) = vpack[ab];
    }
    __syncthreads();

    // ---- Phase 2: 16 ab-GEMMs [32 x 64c] x [64c x 64k]; wave = (mt, kq) ----
    f32x4 acc[16];
    #pragma unroll
    for (int ab = 0; ab < 16; ++ab) acc[ab] = (f32x4){0.f, 0.f, 0.f, 0.f};

    const int arow = lane & 15;
    const int tm_a = mt * 16 + arow;
    const int agrp = lane >> 4;
    const int abase0 = (tm_a * 128 + agrp * 16) ^ ((tm_a & 7) << 4);
    const int abase1 = (tm_a * 128 + agrp * 16 + 64) ^ ((tm_a & 7) << 4);
    const short8* UfV = reinterpret_cast<const short8*>(Uf);

    #pragma unroll 4
    for (int ab = 0; ab < 16; ++ab) {
        short8 A0 = *reinterpret_cast<const short8*>(smem + ab * 4096 + abase0);
        short8 A1 = *reinterpret_cast<const short8*>(smem + ab * 4096 + abase1);
        short8 B0 = UfV[((ab * 2 + 0) * 4 + kq) * 64 + lane];
        short8 B1 = UfV[((ab * 2 + 1) * 4 + kq) * 64 + lane];
        acc[ab] = __builtin_amdgcn_mfma_f32_16x16x32_bf16(A0, B0, acc[ab], 0, 0, 0);
        acc[ab] = __builtin_amdgcn_mfma_f32_16x16x32_bf16(A1, B1, acc[ab], 0, 0, 0);
    }
    __syncthreads();   // all V reads done; smem will be reused for Ys

    // ---- Phase 3: per-lane output transform -> stage f32 Ys in LDS ----
    float* Ys = reinterpret_cast<float*>(smem);
    const int k = kq * 16 + (lane & 15);
    #pragma unroll
    for (int q = 0; q < 4; ++q) {
        const int uu_loc = (lane >> 4) * 4 + q;      // 0..15
        float m[16];
        #pragma unroll
        for (int ab = 0; ab < 16; ++ab) m[ab] = acc[ab][q];
        float w0[4], w1[4];
        #pragma unroll
        for (int b = 0; b < 4; ++b) {
            w0[b] = m[0 + b] + m[4 + b] + m[8 + b];
            w1[b] = m[4 + b] - m[8 + b] - m[12 + b];
        }
        float y00 = w0[0] + w0[1] + w0[2];
        float y01 = w0[1] - w0[2] - w0[3];
        float y10 = w1[0] + w1[1] + w1[2];
        float y11 = w1[1] - w1[2] - w1[3];
        int base = k * 138 + (mt * 2) * 34 + 2 * uu_loc;
        *reinterpret_cast<float2*>(Ys + base)      = make_float2(y00, y01);
        *reinterpret_cast<float2*>(Ys + base + 34) = make_float2(y10, y11);
    }
    __syncthreads();

    // ---- Phase 4: coalesced copy-out; one wave instr = one k-plane, 4x128B rows ----
    #pragma unroll
    for (int i = 0; i < 8; ++i) {
        int f    = tid + 512 * i;          // 0..4095
        int col2 = f & 15;
        int r    = (f >> 4) & 3;
        int kk   = f >> 6;
        float2 v = *reinterpret_cast<const float2*>(Ys + kk * 138 + r * 34 + col2 * 2);
        int row_g = ttb * 4 + r;
        int col_g = uub * 32 + col2 * 2;
        if (row_g < OW && col_g < OW) {
            *reinterpret_cast<float2*>(
                Y + ((size_t)(n * 64 + kk) * OW + row_g) * OW + col_g) = v;
        }
    }
}

extern "C" void kernel_launch(void* const* d_in, const int* in_sizes, int n_in,
                              void* d_out, int out_size, void* d_ws, size_t ws_size,
                              hipStream_t stream) {
    const float* x    = (const float*)d_in[0];
    const float* filt = (const float*)d_in[1];
    float* Y = (float*)d_out;
    unsigned short* Uf = (unsigned short*)d_ws;    // 128 KB bf16 U fragments

    filter_transform<<<16, 256, 0, stream>>>(filt, Uf);

    dim3 grid(128, 8);   // (ttb 32 x uub 4), n
    winograd_main<<<grid, 512, 0, stream>>>(x, Uf, Y);
}

// Round 5
// 94.721 us; speedup vs baseline: 6.0779x; 1.1045x over previous
//
#include <hip/hip_runtime.h>

// Winograd F(2x2,3x3) via bf16 MFMA, full-row output ownership.
// x (8,64,128,128) f32, filt (64,64,3,3) f32 -> Y (8,64,126,126) f32
// Block = (n, 2 tt-rows x all 63 uu) = 126 tiles (pad 128), all 64 k, all 64 c.
// Passes: 2 c-chunks x 4 a-rows; Yt partials accumulate in VGPRs across passes.

#define T_TILES 63
#define HW 128
#define OW 126

typedef __attribute__((ext_vector_type(8))) short short8;   // 8 bf16
typedef __attribute__((ext_vector_type(4))) float f32x4;

static __device__ __forceinline__ unsigned int f2bf(float f) {
    unsigned int u = __float_as_uint(f);
    return (u + 0x7FFFu + ((u >> 16) & 1u)) >> 16;   // RNE bf16
}

// U_frag layout: frag[(ab*2+ch)*4+kq][lane 0..63][j 0..7] bf16  (128 KB total)
// B-operand lane l holds B[c'=(l>>4)*8+j (+32*ch)][k=(l&15)+16*kq]
__global__ __launch_bounds__(256)
void filter_transform(const float* __restrict__ g, unsigned short* __restrict__ Uf) {
    int idx = blockIdx.x * 256 + threadIdx.x;   // k*64 + c
    if (idx >= 64 * 64) return;
    int k = idx >> 6, c = idx & 63;
    const float* gp = g + idx * 9;
    float g00 = gp[0], g01 = gp[1], g02 = gp[2];
    float g10 = gp[3], g11 = gp[4], g12 = gp[5];
    float g20 = gp[6], g21 = gp[7], g22 = gp[8];
    float w[4][3];
    w[0][0] = g00;                w[0][1] = g01;                w[0][2] = g02;
    w[1][0] = 0.5f*(g00+g10+g20); w[1][1] = 0.5f*(g01+g11+g21); w[1][2] = 0.5f*(g02+g12+g22);
    w[2][0] = 0.5f*(g00-g10+g20); w[2][1] = 0.5f*(g01-g11+g21); w[2][2] = 0.5f*(g02-g12+g22);
    w[3][0] = g20;                w[3][1] = g21;                w[3][2] = g22;

    int kq = k >> 4, kl = k & 15;
    int ch = c >> 5;
    int lane = kl + (((c & 31) >> 3) << 4);
    int j = c & 7;
    #pragma unroll
    for (int a = 0; a < 4; ++a) {
        float uv[4];
        uv[0] = w[a][0];
        uv[1] = 0.5f * (w[a][0] + w[a][1] + w[a][2]);
        uv[2] = 0.5f * (w[a][0] - w[a][1] + w[a][2]);
        uv[3] = w[a][2];
        #pragma unroll
        for (int b = 0; b < 4; ++b) {
            int ab = a * 4 + b;
            size_t off = ((size_t)((ab * 2 + ch) * 4 + kq) * 64 + lane) * 8 + j;
            Uf[off] = (unsigned short)f2bf(uv[b]);
        }
    }
}

// V LDS per pass: bf16 [b 4][tm 128][c' 32], byte = b*8192 + ((tm*64 + c'*2) ^ ((tm&7)<<4)).
__global__ __launch_bounds__(512)
void winograd_main(const float* __restrict__ x, const unsigned short* __restrict__ Uf,
                   float* __restrict__ Y) {
    __shared__ __align__(16) char Vs[32768];

    const int tid  = threadIdx.x;
    const int lane = tid & 63;
    const int wv   = tid >> 6;                 // wave id = M-tile (0..7)
    const int n    = blockIdx.y;
    const int tb   = blockIdx.x;               // tt band: tt in {2tb, 2tb+1}

    f32x4 Yp[4][2][2];                          // [kq][p][q] Yt partials
    #pragma unroll
    for (int kq = 0; kq < 4; ++kq)
        #pragma unroll
        for (int p = 0; p < 2; ++p)
            #pragma unroll
            for (int q = 0; q < 2; ++q)
                Yp[kq][p][q] = (f32x4){0.f, 0.f, 0.f, 0.f};

    const short8* UfV = (const short8*)Uf;
    const int tmA   = wv * 16 + (lane & 15);    // A-frag tile row
    const int abase = (tmA * 64 + (lane >> 4) * 16) ^ ((tmA & 7) << 4);

    #pragma unroll
    for (int ch = 0; ch < 2; ++ch) {
        #pragma unroll
        for (int a = 0; a < 4; ++a) {
            // w_a = sA*d[rA] + sB*d[rB]
            const int   rA = (a == 0) ? 0 : 1;
            const int   rB = (a == 3) ? 3 : 2;
            const float sA = (a == 2) ? -1.f : 1.f;
            const float sB = (a == 1 || a == 2) ? 1.f : -1.f;

            // ---- transform phase: 1024 (tm, cg) units, 2 per thread ----
            #pragma unroll
            for (int it = 0; it < 2; ++it) {
                int unit = tid + 512 * it;
                int tm = unit & 127;
                int cg = unit >> 7;             // 4 channels: c' = 4cg..4cg+3
                int tt = tb * 2 + (tm >> 6);
                int uu = tm & 63;
                unsigned int pk[4][2];
                if (tt < T_TILES && uu < T_TILES) {
                    float vb[4][4];             // [h][b]
                    #pragma unroll
                    for (int h = 0; h < 4; ++h) {
                        const float* xp = x + (((size_t)(n * 64 + ch * 32 + cg * 4 + h)) * HW
                                               + 2 * tt) * HW + 2 * uu;
                        const float* pA = xp + rA * HW;
                        const float* pB = xp + rB * HW;
                        float2 A0 = *reinterpret_cast<const float2*>(pA);
                        float2 A1 = *reinterpret_cast<const float2*>(pA + 2);
                        float2 B0 = *reinterpret_cast<const float2*>(pB);
                        float2 B1 = *reinterpret_cast<const float2*>(pB + 2);
                        float w0 = sA * A0.x + sB * B0.x;
                        float w1 = sA * A0.y + sB * B0.y;
                        float w2 = sA * A1.x + sB * B1.x;
                        float w3 = sA * A1.y + sB * B1.y;
                        vb[h][0] = w0 - w2;
                        vb[h][1] = w1 + w2;
                        vb[h][2] = w2 - w1;
                        vb[h][3] = w1 - w3;
                    }
                    #pragma unroll
                    for (int b = 0; b < 4; ++b) {
                        pk[b][0] = f2bf(vb[0][b]) | (f2bf(vb[1][b]) << 16);
                        pk[b][1] = f2bf(vb[2][b]) | (f2bf(vb[3][b]) << 16);
                    }
                } else {
                    #pragma unroll
                    for (int b = 0; b < 4; ++b) { pk[b][0] = 0u; pk[b][1] = 0u; }
                }
                int wbase = (tm * 64 + cg * 8) ^ ((tm & 7) << 4);
                #pragma unroll
                for (int b = 0; b < 4; ++b) {
                    uint2 v; v.x = pk[b][0]; v.y = pk[b][1];
                    *reinterpret_cast<uint2*>(Vs + b * 8192 + wbase) = v;
                }
            }
            __syncthreads();

            // ---- GEMM phase: acc[kq][b] += A[b] x B[ab,kq] ----
            f32x4 acc[4][4];
            #pragma unroll
            for (int kq = 0; kq < 4; ++kq)
                #pragma unroll
                for (int b = 0; b < 4; ++b)
                    acc[kq][b] = (f32x4){0.f, 0.f, 0.f, 0.f};

            short8 Af[4];
            #pragma unroll
            for (int b = 0; b < 4; ++b)
                Af[b] = *reinterpret_cast<const short8*>(Vs + b * 8192 + abase);

            #pragma unroll
            for (int kq = 0; kq < 4; ++kq) {
                #pragma unroll
                for (int b = 0; b < 4; ++b) {
                    short8 Bf = UfV[(size_t)((((a * 4 + b) * 2 + ch) * 4 + kq)) * 64 + lane];
                    acc[kq][b] = __builtin_amdgcn_mfma_f32_16x16x32_bf16(Af[b], Bf, acc[kq][b], 0, 0, 0);
                }
            }

            // ---- fold this a-row into Yt partials (linear in ab) ----
            #pragma unroll
            for (int kq = 0; kq < 4; ++kq) {
                f32x4 t0 = acc[kq][0] + acc[kq][1] + acc[kq][2];
                f32x4 t1 = acc[kq][1] - acc[kq][2] - acc[kq][3];
                if (a == 0) { Yp[kq][0][0] += t0; Yp[kq][0][1] += t1; }
                if (a == 1) { Yp[kq][0][0] += t0; Yp[kq][0][1] += t1;
                              Yp[kq][1][0] += t0; Yp[kq][1][1] += t1; }
                if (a == 2) { Yp[kq][0][0] += t0; Yp[kq][0][1] += t1;
                              Yp[kq][1][0] -= t0; Yp[kq][1][1] -= t1; }
                if (a == 3) { Yp[kq][1][0] -= t0; Yp[kq][1][1] -= t1; }
            }
            __syncthreads();
        }
    }

    // ---- store: full-row ownership, float2 per (tile,k,p) ----
    #pragma unroll
    for (int kq = 0; kq < 4; ++kq) {
        const int kk = kq * 16 + (lane & 15);
        float* Yb = Y + (size_t)(n * 64 + kk) * (OW * OW);
        #pragma unroll
        for (int r = 0; r < 4; ++r) {
            int tm = wv * 16 + 4 * (lane >> 4) + r;
            int uu = tm & 63;
            int row0 = tb * 4 + (tm >> 6) * 2;
            if (uu < T_TILES && row0 < OW) {
                float2 v0 = make_float2(Yp[kq][0][0][r], Yp[kq][0][1][r]);
                float2 v1 = make_float2(Yp[kq][1][0][r], Yp[kq][1][1][r]);
                *reinterpret_cast<float2*>(Yb + (size_t)row0 * OW + 2 * uu)       = v0;
                *reinterpret_cast<float2*>(Yb + (size_t)(row0 + 1) * OW + 2 * uu) = v1;
            }
        }
    }
}

extern "C" void kernel_launch(void* const* d_in, const int* in_sizes, int n_in,
                              void* d_out, int out_size, void* d_ws, size_t ws_size,
                              hipStream_t stream) {
    const float* x    = (const float*)d_in[0];
    const float* filt = (const float*)d_in[1];
    float* Y = (float*)d_out;
    unsigned short* Uf = (unsigned short*)d_ws;    // 128 KB bf16 U fragments

    filter_transform<<<16, 256, 0, stream>>>(filt, Uf);

    dim3 grid(32, 8);   // tt-band, n  -> 256 blocks = 1/CU
    winograd_main<<<grid, 512, 0, stream>>>(x, Uf, Y);
}

// Round 6
// 93.877 us; speedup vs baseline: 6.1326x; 1.0090x over previous
//
#include <hip/hip_runtime.h>

// Winograd F(2x2,3x3) via bf16 MFMA, full-row output ownership,
// a-pair-merged passes + LDS-staged coalesced stores.
// x (8,64,128,128) f32, filt (64,64,3,3) f32 -> Y (8,64,126,126) f32
// Block = (n, 2 tt-rows x all 63 uu) = 126 tiles (pad 128), all 64 k.
// 4 passes: 2 c-chunks x 2 a-pairs; Yt partials accumulate in VGPRs.

#define T_TILES 63
#define HW 128
#define OW 126

typedef __attribute__((ext_vector_type(8))) short short8;   // 8 bf16
typedef __attribute__((ext_vector_type(4))) float f32x4;

static __device__ __forceinline__ unsigned int f2bf(float f) {
    unsigned int u = __float_as_uint(f);
    return (u + 0x7FFFu + ((u >> 16) & 1u)) >> 16;   // RNE bf16
}

// U_frag layout (same as R5): frag[(ab*2+ch)*4+kq][lane 0..63][j 0..7] bf16 (128 KB)
// B-operand lane l holds B[c'=(l>>4)*8+j (+32*ch)][k=(l&15)+16*kq]
__global__ __launch_bounds__(256)
void filter_transform(const float* __restrict__ g, unsigned short* __restrict__ Uf) {
    int idx = blockIdx.x * 256 + threadIdx.x;   // k*64 + c
    if (idx >= 64 * 64) return;
    int k = idx >> 6, c = idx & 63;
    const float* gp = g + idx * 9;
    float g00 = gp[0], g01 = gp[1], g02 = gp[2];
    float g10 = gp[3], g11 = gp[4], g12 = gp[5];
    float g20 = gp[6], g21 = gp[7], g22 = gp[8];
    float w[4][3];
    w[0][0] = g00;                w[0][1] = g01;                w[0][2] = g02;
    w[1][0] = 0.5f*(g00+g10+g20); w[1][1] = 0.5f*(g01+g11+g21); w[1][2] = 0.5f*(g02+g12+g22);
    w[2][0] = 0.5f*(g00-g10+g20); w[2][1] = 0.5f*(g01-g11+g21); w[2][2] = 0.5f*(g02-g12+g22);
    w[3][0] = g20;                w[3][1] = g21;                w[3][2] = g22;

    int kq = k >> 4, kl = k & 15;
    int ch = c >> 5;
    int lane = kl + (((c & 31) >> 3) << 4);
    int j = c & 7;
    #pragma unroll
    for (int a = 0; a < 4; ++a) {
        float uv[4];
        uv[0] = w[a][0];
        uv[1] = 0.5f * (w[a][0] + w[a][1] + w[a][2]);
        uv[2] = 0.5f * (w[a][0] - w[a][1] + w[a][2]);
        uv[3] = w[a][2];
        #pragma unroll
        for (int b = 0; b < 4; ++b) {
            int ab = a * 4 + b;
            size_t off = ((size_t)((ab * 2 + ch) * 4 + kq) * 64 + lane) * 8 + j;
            Uf[off] = (unsigned short)f2bf(uv[b]);
        }
    }
}

// V LDS per pass: bf16 [ai 2][b 4][tm 128][c' 32]
//   byte = (ai*4+b)*8192 + ((tm*64 + cg*16) ^ (((tm>>1)&7)<<4))   (64 KB)
// Store staging (reuses LDS): f32 Ys[k' 16][row 4][col 128], word = k'*513 + row*128 + col
__global__ __launch_bounds__(512)
void winograd_main(const float* __restrict__ x, const unsigned short* __restrict__ Uf,
                   float* __restrict__ Y) {
    __shared__ __align__(16) char smem[65536];

    const int tid  = threadIdx.x;
    const int lane = tid & 63;
    const int wv   = tid >> 6;                 // 0..7
    const int n    = blockIdx.y;
    const int tb   = blockIdx.x;               // tt band: tt in {2tb, 2tb+1}

    f32x4 Yp[4][2][2];                          // [kq][p][q] Yt partials
    #pragma unroll
    for (int kq = 0; kq < 4; ++kq)
        #pragma unroll
        for (int p = 0; p < 2; ++p)
            #pragma unroll
            for (int q = 0; q < 2; ++q)
                Yp[kq][p][q] = (f32x4){0.f, 0.f, 0.f, 0.f};

    const short8* UfV = (const short8*)Uf;
    const int tmA   = wv * 16 + (lane & 15);    // A-frag tile row
    const int cgrp  = lane >> 4;
    const int abase = (tmA * 64 + cgrp * 16) ^ (((tmA >> 1) & 7) << 4);

    const int tm = tid & 127;
    const int cg = tid >> 7;                    // c-group: 8 channels each
    const int tt = tb * 2 + (tm >> 6);
    const int uu = tm & 63;
    const int wb = (tm * 64 + cg * 16) ^ (((tm >> 1) & 7) << 4);

    #pragma unroll
    for (int ch = 0; ch < 2; ++ch) {
        #pragma unroll
        for (int P = 0; P < 2; ++P) {           // a-pair: a in {2P, 2P+1}
            // ---- transform: rows 2tt+P .. 2tt+P+2, 8 channels per thread ----
            unsigned int pk[2][4][4];
            #pragma unroll
            for (int ai = 0; ai < 2; ++ai)
                #pragma unroll
                for (int b = 0; b < 4; ++b)
                    #pragma unroll
                    for (int q = 0; q < 4; ++q) pk[ai][b][q] = 0u;

            if (tt < T_TILES && uu < T_TILES) {
                #pragma unroll 2
                for (int h = 0; h < 8; ++h) {
                    const float* xp = x + (((size_t)(n * 64 + ch * 32 + cg * 8 + h)) * HW
                                           + 2 * tt + P) * HW + 2 * uu;
                    float ld[3][4];
                    #pragma unroll
                    for (int rr = 0; rr < 3; ++rr) {
                        float2 lo = *reinterpret_cast<const float2*>(xp + rr * HW);
                        float2 hi = *reinterpret_cast<const float2*>(xp + rr * HW + 2);
                        ld[rr][0] = lo.x; ld[rr][1] = lo.y; ld[rr][2] = hi.x; ld[rr][3] = hi.y;
                    }
                    float wa[2][4];
                    #pragma unroll
                    for (int j = 0; j < 4; ++j) {
                        if (P == 0) {
                            wa[0][j] = ld[0][j] - ld[2][j];   // a=0: d0 - d2
                            wa[1][j] = ld[1][j] + ld[2][j];   // a=1: d1 + d2
                        } else {
                            wa[0][j] = ld[1][j] - ld[0][j];   // a=2: d2 - d1
                            wa[1][j] = ld[0][j] - ld[2][j];   // a=3: d1 - d3
                        }
                    }
                    #pragma unroll
                    for (int ai = 0; ai < 2; ++ai) {
                        float v0 = wa[ai][0] - wa[ai][2];
                        float v1 = wa[ai][1] + wa[ai][2];
                        float v2 = wa[ai][2] - wa[ai][1];
                        float v3 = wa[ai][1] - wa[ai][3];
                        int sh = 16 * (h & 1);
                        pk[ai][0][h >> 1] |= f2bf(v0) << sh;
                        pk[ai][1][h >> 1] |= f2bf(v1) << sh;
                        pk[ai][2][h >> 1] |= f2bf(v2) << sh;
                        pk[ai][3][h >> 1] |= f2bf(v3) << sh;
                    }
                }
            }
            #pragma unroll
            for (int ai = 0; ai < 2; ++ai)
                #pragma unroll
                for (int b = 0; b < 4; ++b) {
                    uint4 v; v.x = pk[ai][b][0]; v.y = pk[ai][b][1];
                    v.z = pk[ai][b][2]; v.w = pk[ai][b][3];
                    *reinterpret_cast<uint4*>(smem + (ai * 4 + b) * 8192 + wb) = v;
                }
            __syncthreads();

            // ---- GEMM + fold ----
            #pragma unroll
            for (int ai = 0; ai < 2; ++ai) {
                const int a = P * 2 + ai;
                short8 Af[4];
                #pragma unroll
                for (int b = 0; b < 4; ++b)
                    Af[b] = *reinterpret_cast<const short8*>(
                        smem + (ai * 4 + b) * 8192 + abase);
                f32x4 acc[4][4];
                #pragma unroll
                for (int kq = 0; kq < 4; ++kq)
                    #pragma unroll
                    for (int b = 0; b < 4; ++b)
                        acc[kq][b] = (f32x4){0.f, 0.f, 0.f, 0.f};
                #pragma unroll
                for (int kq = 0; kq < 4; ++kq)
                    #pragma unroll
                    for (int b = 0; b < 4; ++b) {
                        short8 Bf = UfV[(size_t)(((a * 4 + b) * 2 + ch) * 4 + kq) * 64 + lane];
                        acc[kq][b] = __builtin_amdgcn_mfma_f32_16x16x32_bf16(
                            Af[b], Bf, acc[kq][b], 0, 0, 0);
                    }
                #pragma unroll
                for (int kq = 0; kq < 4; ++kq) {
                    f32x4 t0 = acc[kq][0] + acc[kq][1] + acc[kq][2];
                    f32x4 t1 = acc[kq][1] - acc[kq][2] - acc[kq][3];
                    if (a == 0) { Yp[kq][0][0] += t0; Yp[kq][0][1] += t1; }
                    if (a == 1) { Yp[kq][0][0] += t0; Yp[kq][0][1] += t1;
                                  Yp[kq][1][0] += t0; Yp[kq][1][1] += t1; }
                    if (a == 2) { Yp[kq][0][0] += t0; Yp[kq][0][1] += t1;
                                  Yp[kq][1][0] -= t0; Yp[kq][1][1] -= t1; }
                    if (a == 3) { Yp[kq][1][0] -= t0; Yp[kq][1][1] -= t1; }
                }
            }
            __syncthreads();
        }
    }

    // ---- store: stage per kq in LDS, then full-row coalesced 504B stores ----
    float* Ys = reinterpret_cast<float*>(smem);
    const int kl = lane & 15;
    const int g  = lane >> 4;
    #pragma unroll
    for (int kq = 0; kq < 4; ++kq) {
        __syncthreads();   // previous reads of smem done
        #pragma unroll
        for (int r = 0; r < 4; ++r) {
            int tms = wv * 16 + 4 * g + r;
            int row_loc = (tms >> 6) * 2;
            int col = 2 * (tms & 63);
            #pragma unroll
            for (int p = 0; p < 2; ++p) {
                float2 v = make_float2(Yp[kq][p][0][r], Yp[kq][p][1][r]);
                *reinterpret_cast<float2*>(Ys + kl * 513 + (row_loc + p) * 128 + col) = v;
            }
        }
        __syncthreads();
        #pragma unroll
        for (int i = 0; i < 8; ++i) {
            int pair = wv * 8 + i;            // 0..63
            int kp  = pair >> 2;
            int row = pair & 3;
            int row_g = tb * 4 + row;
            if (lane < 63 && row_g < OW) {
                float2 v = *reinterpret_cast<const float2*>(
                    Ys + kp * 513 + row * 128 + 2 * lane);
                *reinterpret_cast<float2*>(
                    Y + (size_t)(n * 64 + kq * 16 + kp) * (OW * OW)
                      + (size_t)row_g * OW + 2 * lane) = v;
            }
        }
    }
}

extern "C" void kernel_launch(void* const* d_in, const int* in_sizes, int n_in,
                              void* d_out, int out_size, void* d_ws, size_t ws_size,
                              hipStream_t stream) {
    const float* x    = (const float*)d_in[0];
    const float* filt = (const float*)d_in[1];
    float* Y = (float*)d_out;
    unsigned short* Uf = (unsigned short*)d_ws;    // 128 KB bf16 U fragments

    filter_transform<<<16, 256, 0, stream>>>(filt, Uf);

    dim3 grid(32, 8);   // tt-band, n  -> 256 blocks = 1/CU
    winograd_main<<<grid, 512, 0, stream>>>(x, Uf, Y);
}

// Round 7
// 90.103 us; speedup vs baseline: 6.3895x; 1.0419x over previous
//
#include <hip/hip_runtime.h>

// Winograd F(2x2,3x3) via bf16 MFMA.
// x (8,64,128,128) f32, filt (64,64,3,3) f32 -> Y (8,64,126,126) f32
// Block = (n, ONE tt row x all 63 uu) = 63 tiles (pad 64), all 64 k, all 64 c.
// Grid 504 = 2 blocks/CU. XCD-swizzled: XCD x owns n=x with contiguous tb.
// 4 passes: 2 c-chunks x 2 a-pairs; Yt partials accumulate in VGPRs.

#define T_TILES 63
#define HW 128
#define OW 126

typedef __attribute__((ext_vector_type(8))) short short8;   // 8 bf16
typedef __attribute__((ext_vector_type(4))) float f32x4;

static __device__ __forceinline__ unsigned int f2bf(float f) {
    unsigned int u = __float_as_uint(f);
    return (u + 0x7FFFu + ((u >> 16) & 1u)) >> 16;   // RNE bf16
}

// U_frag layout (same as R5/R6): frag[(ab*2+ch)*4+kq][lane 0..63][j 0..7] bf16 (128 KB)
// B-operand lane l holds B[c'=(l>>4)*8+j (+32*ch)][k=(l&15)+16*kq]
__global__ __launch_bounds__(256)
void filter_transform(const float* __restrict__ g, unsigned short* __restrict__ Uf) {
    int idx = blockIdx.x * 256 + threadIdx.x;   // k*64 + c
    if (idx >= 64 * 64) return;
    int k = idx >> 6, c = idx & 63;
    const float* gp = g + idx * 9;
    float g00 = gp[0], g01 = gp[1], g02 = gp[2];
    float g10 = gp[3], g11 = gp[4], g12 = gp[5];
    float g20 = gp[6], g21 = gp[7], g22 = gp[8];
    float w[4][3];
    w[0][0] = g00;                w[0][1] = g01;                w[0][2] = g02;
    w[1][0] = 0.5f*(g00+g10+g20); w[1][1] = 0.5f*(g01+g11+g21); w[1][2] = 0.5f*(g02+g12+g22);
    w[2][0] = 0.5f*(g00-g10+g20); w[2][1] = 0.5f*(g01-g11+g21); w[2][2] = 0.5f*(g02-g12+g22);
    w[3][0] = g20;                w[3][1] = g21;                w[3][2] = g22;

    int kq = k >> 4, kl = k & 15;
    int ch = c >> 5;
    int lane = kl + (((c & 31) >> 3) << 4);
    int j = c & 7;
    #pragma unroll
    for (int a = 0; a < 4; ++a) {
        float uv[4];
        uv[0] = w[a][0];
        uv[1] = 0.5f * (w[a][0] + w[a][1] + w[a][2]);
        uv[2] = 0.5f * (w[a][0] - w[a][1] + w[a][2]);
        uv[3] = w[a][2];
        #pragma unroll
        for (int b = 0; b < 4; ++b) {
            int ab = a * 4 + b;
            size_t off = ((size_t)((ab * 2 + ch) * 4 + kq) * 64 + lane) * 8 + j;
            Uf[off] = (unsigned short)f2bf(uv[b]);
        }
    }
}

// V LDS per pass: bf16 [ai 2][b 4][tm 64][c' 32]
//   byte = (ai*4+b)*4096 + tm*64 + ((cslot) ^ ((tm&3)<<4))   (32 KB)
// Store staging (reuses LDS): f32 Ys[k 64][p 2][col 128], word = k*258 + p*128 + col (66048 B)
__global__ __launch_bounds__(512, 4)
void winograd_main(const float* __restrict__ x, const unsigned short* __restrict__ Uf,
                   float* __restrict__ Y) {
    extern __shared__ __align__(16) char smem[];

    const int tid  = threadIdx.x;
    const int lane = tid & 63;
    const int wv   = tid >> 6;                 // 0..7

    // XCD-bijective swizzle: 504 = 8 XCDs x 63. XCD x -> n=x, tb contiguous.
    const int lin = blockIdx.x;
    const int swz = (lin & 7) * 63 + (lin >> 3);
    const int n   = swz / 63;
    const int tb  = swz % 63;                  // tt (single tile row)

    const int mt  = wv >> 1;                   // 0..3  M-tile
    const int kqh = wv & 1;                    // 0..1  k-half

    f32x4 Yp[2][2][2];                          // [kq2][p][q]
    #pragma unroll
    for (int kq2 = 0; kq2 < 2; ++kq2)
        #pragma unroll
        for (int p = 0; p < 2; ++p)
            #pragma unroll
            for (int q = 0; q < 2; ++q)
                Yp[kq2][p][q] = (f32x4){0.f, 0.f, 0.f, 0.f};

    const short8* UfV = (const short8*)Uf;
    const int kl = lane & 15;
    const int g4 = lane >> 4;                  // 0..3
    const int tmA   = mt * 16 + kl;
    const int abase = tmA * 64 + ((g4 * 16) ^ ((tmA & 3) << 4));

    const int tm = lane;                        // uu (0..63)
    const int cg = wv;                          // c-group (4 channels)
    const int wbase = tm * 64 + ((cg * 8) ^ ((tm & 3) << 4));
    const bool valid = (tm < T_TILES);

    #pragma unroll
    for (int ch = 0; ch < 2; ++ch) {
        #pragma unroll
        for (int P = 0; P < 2; ++P) {           // a-pair: a in {2P, 2P+1}
            // ---- transform: x rows 2tb+P..2tb+P+2, 4 channels per thread ----
            unsigned int pk[2][4][2];
            #pragma unroll
            for (int ai = 0; ai < 2; ++ai)
                #pragma unroll
                for (int b = 0; b < 4; ++b) { pk[ai][b][0] = 0u; pk[ai][b][1] = 0u; }

            if (valid) {
                #pragma unroll
                for (int h = 0; h < 4; ++h) {
                    const float* xp = x + (((size_t)(n * 64 + ch * 32 + cg * 4 + h)) * HW
                                           + 2 * tb + P) * HW + 2 * tm;
                    float ld[3][4];
                    #pragma unroll
                    for (int rr = 0; rr < 3; ++rr) {
                        float2 lo = *reinterpret_cast<const float2*>(xp + rr * HW);
                        float2 hi = *reinterpret_cast<const float2*>(xp + rr * HW + 2);
                        ld[rr][0] = lo.x; ld[rr][1] = lo.y; ld[rr][2] = hi.x; ld[rr][3] = hi.y;
                    }
                    float wa[2][4];
                    #pragma unroll
                    for (int j = 0; j < 4; ++j) {
                        if (P == 0) {
                            wa[0][j] = ld[0][j] - ld[2][j];   // a=0: d0 - d2
                            wa[1][j] = ld[1][j] + ld[2][j];   // a=1: d1 + d2
                        } else {
                            wa[0][j] = ld[1][j] - ld[0][j];   // a=2: d2 - d1
                            wa[1][j] = ld[0][j] - ld[2][j];   // a=3: d1 - d3
                        }
                    }
                    const int sh = (h & 1) * 16;
                    const int wd = h >> 1;
                    #pragma unroll
                    for (int ai = 0; ai < 2; ++ai) {
                        pk[ai][0][wd] |= f2bf(wa[ai][0] - wa[ai][2]) << sh;
                        pk[ai][1][wd] |= f2bf(wa[ai][1] + wa[ai][2]) << sh;
                        pk[ai][2][wd] |= f2bf(wa[ai][2] - wa[ai][1]) << sh;
                        pk[ai][3][wd] |= f2bf(wa[ai][1] - wa[ai][3]) << sh;
                    }
                }
            }
            #pragma unroll
            for (int ai = 0; ai < 2; ++ai)
                #pragma unroll
                for (int b = 0; b < 4; ++b) {
                    uint2 v; v.x = pk[ai][b][0]; v.y = pk[ai][b][1];
                    *reinterpret_cast<uint2*>(smem + (ai * 4 + b) * 4096 + wbase) = v;
                }
            __syncthreads();

            // ---- GEMM + fold ----
            #pragma unroll
            for (int ai = 0; ai < 2; ++ai) {
                const int a = P * 2 + ai;
                short8 Af[4];
                #pragma unroll
                for (int b = 0; b < 4; ++b)
                    Af[b] = *reinterpret_cast<const short8*>(
                        smem + (ai * 4 + b) * 4096 + abase);
                f32x4 acc[2][4];
                #pragma unroll
                for (int kq2 = 0; kq2 < 2; ++kq2)
                    #pragma unroll
                    for (int b = 0; b < 4; ++b)
                        acc[kq2][b] = (f32x4){0.f, 0.f, 0.f, 0.f};
                #pragma unroll
                for (int kq2 = 0; kq2 < 2; ++kq2) {
                    const int kq = kqh * 2 + kq2;
                    #pragma unroll
                    for (int b = 0; b < 4; ++b) {
                        short8 Bf = UfV[(size_t)(((a * 4 + b) * 2 + ch) * 4 + kq) * 64 + lane];
                        acc[kq2][b] = __builtin_amdgcn_mfma_f32_16x16x32_bf16(
                            Af[b], Bf, acc[kq2][b], 0, 0, 0);
                    }
                }
                #pragma unroll
                for (int kq2 = 0; kq2 < 2; ++kq2) {
                    f32x4 t0 = acc[kq2][0] + acc[kq2][1] + acc[kq2][2];
                    f32x4 t1 = acc[kq2][1] - acc[kq2][2] - acc[kq2][3];
                    if (a == 0) { Yp[kq2][0][0] += t0; Yp[kq2][0][1] += t1; }
                    if (a == 1) { Yp[kq2][0][0] += t0; Yp[kq2][0][1] += t1;
                                  Yp[kq2][1][0] += t0; Yp[kq2][1][1] += t1; }
                    if (a == 2) { Yp[kq2][0][0] += t0; Yp[kq2][0][1] += t1;
                                  Yp[kq2][1][0] -= t0; Yp[kq2][1][1] -= t1; }
                    if (a == 3) { Yp[kq2][1][0] -= t0; Yp[kq2][1][1] -= t1; }
                }
            }
            __syncthreads();
        }
    }

    // ---- store: stage all 64 k-planes in LDS, then full-row coalesced stores ----
    float* Ys = reinterpret_cast<float*>(smem);
    #pragma unroll
    for (int kq2 = 0; kq2 < 2; ++kq2) {
        const int k = (kqh * 2 + kq2) * 16 + kl;
        #pragma unroll
        for (int r = 0; r < 4; ++r) {
            const int uu = mt * 16 + 4 * g4 + r;
            #pragma unroll
            for (int p = 0; p < 2; ++p) {
                *reinterpret_cast<float2*>(Ys + k * 258 + p * 128 + 2 * uu) =
                    make_float2(Yp[kq2][p][0][r], Yp[kq2][p][1][r]);
            }
        }
    }
    __syncthreads();
    #pragma unroll
    for (int i = 0; i < 16; ++i) {
        const int unit = wv * 16 + i;          // 0..127
        const int kp = unit >> 1;              // 0..63
        const int p  = unit & 1;
        if (lane < 63) {
            float2 v = *reinterpret_cast<const float2*>(Ys + kp * 258 + p * 128 + 2 * lane);
            *reinterpret_cast<float2*>(
                Y + (size_t)(n * 64 + kp) * (OW * OW)
                  + (size_t)(2 * tb + p) * OW + 2 * lane) = v;
        }
    }
}

extern "C" void kernel_launch(void* const* d_in, const int* in_sizes, int n_in,
                              void* d_out, int out_size, void* d_ws, size_t ws_size,
                              hipStream_t stream) {
    const float* x    = (const float*)d_in[0];
    const float* filt = (const float*)d_in[1];
    float* Y = (float*)d_out;
    unsigned short* Uf = (unsigned short*)d_ws;    // 128 KB bf16 U fragments

    filter_transform<<<16, 256, 0, stream>>>(filt, Uf);

    winograd_main<<<dim3(504), 512, 66048, stream>>>(x, Uf, Y);
}

// Round 8
// 71.075 us; speedup vs baseline: 8.1000x; 1.2677x over previous
//
#include <hip/hip_runtime.h>

// Winograd F(2x2,3x3) via bf16 MFMA, kq-split blocks + plane-contiguous output.
// x (8,64,128,128) f32, filt (64,64,3,3) f32 -> Y (8,64,126,126) f32
// Block = (n, kq: 16 k, band: 3 tt rows = 6 output rows, all 63 uu, all 64 c).
// Grid 672 = 8 n x 4 kq x 21 tb; blockIdx&7 = n -> all of an image on one XCD.
// 6 passes: 3 tt x 2 ch(32c); all 16 ab per pass (V = 64 KB LDS).

#define T_TILES 63
#define HW 128
#define OW 126

typedef __attribute__((ext_vector_type(8))) short short8;   // 8 bf16
typedef __attribute__((ext_vector_type(4))) float f32x4;

static __device__ __forceinline__ unsigned int f2bf(float f) {
    unsigned int u = __float_as_uint(f);
    return (u + 0x7FFFu + ((u >> 16) & 1u)) >> 16;   // RNE bf16
}

// U_frag layout (unchanged): frag[(ab*2+ch)*4+kq][lane 0..63][j 0..7] bf16 (128 KB)
// B-operand lane l holds B[c'=(l>>4)*8+j (+32*ch)][k=(l&15)+16*kq]
__global__ __launch_bounds__(256)
void filter_transform(const float* __restrict__ g, unsigned short* __restrict__ Uf) {
    int idx = blockIdx.x * 256 + threadIdx.x;   // k*64 + c
    if (idx >= 64 * 64) return;
    int k = idx >> 6, c = idx & 63;
    const float* gp = g + idx * 9;
    float g00 = gp[0], g01 = gp[1], g02 = gp[2];
    float g10 = gp[3], g11 = gp[4], g12 = gp[5];
    float g20 = gp[6], g21 = gp[7], g22 = gp[8];
    float w[4][3];
    w[0][0] = g00;                w[0][1] = g01;                w[0][2] = g02;
    w[1][0] = 0.5f*(g00+g10+g20); w[1][1] = 0.5f*(g01+g11+g21); w[1][2] = 0.5f*(g02+g12+g22);
    w[2][0] = 0.5f*(g00-g10+g20); w[2][1] = 0.5f*(g01-g11+g21); w[2][2] = 0.5f*(g02-g12+g22);
    w[3][0] = g20;                w[3][1] = g21;                w[3][2] = g22;

    int kq = k >> 4, kl = k & 15;
    int ch = c >> 5;
    int lane = kl + (((c & 31) >> 3) << 4);
    int j = c & 7;
    #pragma unroll
    for (int a = 0; a < 4; ++a) {
        float uv[4];
        uv[0] = w[a][0];
        uv[1] = 0.5f * (w[a][0] + w[a][1] + w[a][2]);
        uv[2] = 0.5f * (w[a][0] - w[a][1] + w[a][2]);
        uv[3] = w[a][2];
        #pragma unroll
        for (int b = 0; b < 4; ++b) {
            int ab = a * 4 + b;
            size_t off = ((size_t)((ab * 2 + ch) * 4 + kq) * 64 + lane) * 8 + j;
            Uf[off] = (unsigned short)f2bf(uv[b]);
        }
    }
}

// V LDS per pass: bf16 [ab 16][tm 64][c' 32]
//   byte = ab*4096 + tm*64 + ((c-byte-off) ^ ((tm&3)<<4))     (64 KB)
// Store staging (reuses LDS): f32 Ys[k' 16][row 6][col 126], word = k'*764 + row*126 + col
__global__ __launch_bounds__(512, 4)
void winograd_main(const float* __restrict__ x, const unsigned short* __restrict__ Uf,
                   float* __restrict__ Y) {
    __shared__ __align__(16) char smem[65536];

    const int tid  = threadIdx.x;
    const int lane = tid & 63;
    const int wv   = tid >> 6;                 // 0..7

    const int n  = blockIdx.x & 7;             // XCD id (round-robin heuristic)
    const int r2 = blockIdx.x >> 3;
    const int kq = r2 & 3;
    const int tb = r2 >> 2;                    // 0..20  (6-row band)

    const int mt = wv >> 1;                    // 0..3 M-tile (16 uu each)
    const int ai = wv & 1;                     // a-pair half: a in {2ai, 2ai+1}

    const int kl = lane & 15;
    const int g4 = lane >> 4;

    f32x4 Yp[3][2][2];                          // [tt][p][q]
    #pragma unroll
    for (int t = 0; t < 3; ++t)
        #pragma unroll
        for (int p = 0; p < 2; ++p)
            #pragma unroll
            for (int q = 0; q < 2; ++q)
                Yp[t][p][q] = (f32x4){0.f, 0.f, 0.f, 0.f};

    // transform mapping: tm = uu tile (0..63), cg = c-group of 4 channels
    const int tm = lane;
    const int cg = wv;
    const bool tvalid = (tm < T_TILES);

    // A-fragment read base
    const int tmA   = mt * 16 + kl;
    const int abase = tmA * 64 + ((g4 * 16) ^ ((tmA & 3) << 4));

    const short8* UfV = (const short8*)Uf;

    #pragma unroll
    for (int tt = 0; tt < 3; ++tt) {
        const int xrow0 = 6 * tb + 2 * tt;      // rows xrow0..xrow0+3 (max 127)
        #pragma unroll
        for (int ch = 0; ch < 2; ++ch) {
            // ---- transform: all 16 ab for 64 tm x 32 c' ----
            unsigned int pk[16];                // one 2-c' word per ab per h-pair
            #pragma unroll
            for (int hp = 0; hp < 2; ++hp) {    // h-pair: channels 2hp, 2hp+1
                #pragma unroll
                for (int e = 0; e < 16; ++e) pk[e] = 0u;
                if (tvalid) {
                    #pragma unroll
                    for (int hh = 0; hh < 2; ++hh) {
                        const int c = ch * 32 + cg * 4 + hp * 2 + hh;
                        const float* xp = x + (((size_t)(n * 64 + c)) * HW + xrow0) * HW + 2 * tm;
                        float d[4][4];
                        #pragma unroll
                        for (int rr = 0; rr < 4; ++rr) {
                            float2 lo = *reinterpret_cast<const float2*>(xp + rr * HW);
                            float2 hi = *reinterpret_cast<const float2*>(xp + rr * HW + 2);
                            d[rr][0] = lo.x; d[rr][1] = lo.y; d[rr][2] = hi.x; d[rr][3] = hi.y;
                        }
                        float w[4][4];
                        #pragma unroll
                        for (int j = 0; j < 4; ++j) {
                            w[0][j] = d[0][j] - d[2][j];
                            w[1][j] = d[1][j] + d[2][j];
                            w[2][j] = d[2][j] - d[1][j];
                            w[3][j] = d[1][j] - d[3][j];
                        }
                        const int sh = hh * 16;
                        #pragma unroll
                        for (int a = 0; a < 4; ++a) {
                            pk[a*4+0] |= f2bf(w[a][0] - w[a][2]) << sh;
                            pk[a*4+1] |= f2bf(w[a][1] + w[a][2]) << sh;
                            pk[a*4+2] |= f2bf(w[a][2] - w[a][1]) << sh;
                            pk[a*4+3] |= f2bf(w[a][1] - w[a][3]) << sh;
                        }
                    }
                }
                const int wb = tm * 64 + ((cg * 8 + hp * 4) ^ ((tm & 3) << 4));
                #pragma unroll
                for (int ab = 0; ab < 16; ++ab)
                    *reinterpret_cast<unsigned int*>(smem + ab * 4096 + wb) = pk[ab];
            }
            __syncthreads();

            // ---- GEMM: wave (mt, ai): a in {2ai, 2ai+1}, 4 b, 16 k ----
            f32x4 acc[2][4];
            #pragma unroll
            for (int aa = 0; aa < 2; ++aa)
                #pragma unroll
                for (int b = 0; b < 4; ++b)
                    acc[aa][b] = (f32x4){0.f, 0.f, 0.f, 0.f};

            #pragma unroll
            for (int aa = 0; aa < 2; ++aa) {
                const int a = 2 * ai + aa;
                short8 Af[4];
                #pragma unroll
                for (int b = 0; b < 4; ++b)
                    Af[b] = *reinterpret_cast<const short8*>(
                        smem + (a * 4 + b) * 4096 + abase);
                #pragma unroll
                for (int b = 0; b < 4; ++b) {
                    short8 Bf = UfV[(size_t)(((a * 4 + b) * 2 + ch) * 4 + kq) * 64 + lane];
                    acc[aa][b] = __builtin_amdgcn_mfma_f32_16x16x32_bf16(
                        Af[b], Bf, acc[aa][b], 0, 0, 0);
                }
            }

            // ---- fold (linear in partial sums) ----
            #pragma unroll
            for (int aa = 0; aa < 2; ++aa) {
                const int a = 2 * ai + aa;
                f32x4 t0 = acc[aa][0] + acc[aa][1] + acc[aa][2];
                f32x4 t1 = acc[aa][1] - acc[aa][2] - acc[aa][3];
                if (a == 0) { Yp[tt][0][0] += t0; Yp[tt][0][1] += t1; }
                if (a == 1) { Yp[tt][0][0] += t0; Yp[tt][0][1] += t1;
                              Yp[tt][1][0] += t0; Yp[tt][1][1] += t1; }
                if (a == 2) { Yp[tt][0][0] += t0; Yp[tt][0][1] += t1;
                              Yp[tt][1][0] -= t0; Yp[tt][1][1] -= t1; }
                if (a == 3) { Yp[tt][1][0] -= t0; Yp[tt][1][1] -= t1; }
            }
            __syncthreads();
        }
    }

    // ---- store: merge ai halves in LDS, then plane-contiguous float4 copy ----
    float* Ys = reinterpret_cast<float*>(smem);
    if (ai == 0) {
        #pragma unroll
        for (int tt = 0; tt < 3; ++tt)
            #pragma unroll
            for (int r = 0; r < 4; ++r) {
                const int uu = mt * 16 + 4 * g4 + r;
                if (uu < T_TILES) {
                    #pragma unroll
                    for (int p = 0; p < 2; ++p)
                        *reinterpret_cast<float2*>(Ys + kl * 764 + (2 * tt + p) * 126 + 2 * uu)
                            = make_float2(Yp[tt][p][0][r], Yp[tt][p][1][r]);
                }
            }
    }
    __syncthreads();
    if (ai == 1) {
        #pragma unroll
        for (int tt = 0; tt < 3; ++tt)
            #pragma unroll
            for (int r = 0; r < 4; ++r) {
                const int uu = mt * 16 + 4 * g4 + r;
                if (uu < T_TILES) {
                    #pragma unroll
                    for (int p = 0; p < 2; ++p) {
                        float2* ptr = reinterpret_cast<float2*>(
                            Ys + kl * 764 + (2 * tt + p) * 126 + 2 * uu);
                        float2 v = *ptr;
                        v.x += Yp[tt][p][0][r];
                        v.y += Yp[tt][p][1][r];
                        *ptr = v;
                    }
                }
            }
    }
    __syncthreads();

    // copy out: 16 planes x 756 floats (6 rows x 126), 189 float4 per plane
    const int kp = tid >> 5;                    // 0..15
    const int lx = tid & 31;
    const float* src = Ys + kp * 764;
    float* dst = Y + ((size_t)(n * 64 + kq * 16 + kp)) * (OW * OW) + 756 * tb;
    #pragma unroll
    for (int it = 0; it < 6; ++it) {
        int idx = it * 32 + lx;
        if (idx < 189) {
            float4 v = *reinterpret_cast<const float4*>(src + 4 * idx);
            *reinterpret_cast<float4*>(dst + 4 * idx) = v;
        }
    }
}

extern "C" void kernel_launch(void* const* d_in, const int* in_sizes, int n_in,
                              void* d_out, int out_size, void* d_ws, size_t ws_size,
                              hipStream_t stream) {
    const float* x    = (const float*)d_in[0];
    const float* filt = (const float*)d_in[1];
    float* Y = (float*)d_out;
    unsigned short* Uf = (unsigned short*)d_ws;    // 128 KB bf16 U fragments

    filter_transform<<<16, 256, 0, stream>>>(filt, Uf);

    winograd_main<<<dim3(672), 512, 0, stream>>>(x, Uf, Y);
}

// Round 9
// 57.940 us; speedup vs baseline: 9.9363x; 1.2267x over previous
//
#include <hip/hip_runtime.h>
#include <hip/hip_bf16.h>

// Winograd F(2x2,3x3) via bf16 MFMA, kq-split blocks + plane-contiguous output.
// x (8,64,128,128) f32, filt (64,64,3,3) f32 -> Y (8,64,126,126) f32
// Block = (n, kq: 16 k, band: 3 tt rows = 6 output rows, all 63 uu, all 64 c).
// Grid 672 = 8 n x 4 kq x 21 tb; blockIdx&7 = n -> all of an image on one XCD.
// 6 passes: 3 tt x 2 ch(32c); all 16 ab per pass.
// V LDS: bf16 [ab 16][tm 64][c' 32], row stride 72 B (8B pad) -> 16-bank spread.

#define T_TILES 63
#define HW 128
#define OW 126

typedef __attribute__((ext_vector_type(8))) short short8;   // 8 bf16
typedef __attribute__((ext_vector_type(4))) float f32x4;

static __device__ __forceinline__ unsigned int f2bf(float f) {
    unsigned int u = __float_as_uint(f);
    return (u + 0x7FFFu + ((u >> 16) & 1u)) >> 16;   // RNE bf16
}

static __device__ __forceinline__ unsigned int pkbf2(float lo, float hi) {
    __hip_bfloat162 t;
    t.x = __float2bfloat16(lo);
    t.y = __float2bfloat16(hi);
    unsigned int r;
    __builtin_memcpy(&r, &t, 4);
    return r;                                   // compiler fuses to v_cvt_pk_bf16_f32
}

// U_frag layout (unchanged): frag[(ab*2+ch)*4+kq][lane 0..63][j 0..7] bf16 (128 KB)
// B-operand lane l holds B[c'=(l>>4)*8+j (+32*ch)][k=(l&15)+16*kq]
__global__ __launch_bounds__(256)
void filter_transform(const float* __restrict__ g, unsigned short* __restrict__ Uf) {
    int idx = blockIdx.x * 256 + threadIdx.x;   // k*64 + c
    if (idx >= 64 * 64) return;
    int k = idx >> 6, c = idx & 63;
    const float* gp = g + idx * 9;
    float g00 = gp[0], g01 = gp[1], g02 = gp[2];
    float g10 = gp[3], g11 = gp[4], g12 = gp[5];
    float g20 = gp[6], g21 = gp[7], g22 = gp[8];
    float w[4][3];
    w[0][0] = g00;                w[0][1] = g01;                w[0][2] = g02;
    w[1][0] = 0.5f*(g00+g10+g20); w[1][1] = 0.5f*(g01+g11+g21); w[1][2] = 0.5f*(g02+g12+g22);
    w[2][0] = 0.5f*(g00-g10+g20); w[2][1] = 0.5f*(g01-g11+g21); w[2][2] = 0.5f*(g02-g12+g22);
    w[3][0] = g20;                w[3][1] = g21;                w[3][2] = g22;

    int kq = k >> 4, kl = k & 15;
    int ch = c >> 5;
    int lane = kl + (((c & 31) >> 3) << 4);
    int j = c & 7;
    #pragma unroll
    for (int a = 0; a < 4; ++a) {
        float uv[4];
        uv[0] = w[a][0];
        uv[1] = 0.5f * (w[a][0] + w[a][1] + w[a][2]);
        uv[2] = 0.5f * (w[a][0] - w[a][1] + w[a][2]);
        uv[3] = w[a][2];
        #pragma unroll
        for (int b = 0; b < 4; ++b) {
            int ab = a * 4 + b;
            size_t off = ((size_t)((ab * 2 + ch) * 4 + kq) * 64 + lane) * 8 + j;
            Uf[off] = (unsigned short)f2bf(uv[b]);
        }
    }
}

#define VSTRIDE 72                    // bytes per tm row (64 data + 8 pad)
#define VPLANE  (64 * VSTRIDE)        // 4608 B per ab plane; total 73728 B
#define YSTRIDE 766                   // f32 words per k-plane in staging

__global__ __launch_bounds__(512, 4)
void winograd_main(const float* __restrict__ x, const unsigned short* __restrict__ Uf,
                   float* __restrict__ Y) {
    extern __shared__ __align__(16) char smem[];

    const int tid  = threadIdx.x;
    const int lane = tid & 63;
    const int wv   = tid >> 6;                 // 0..7

    const int n  = blockIdx.x & 7;             // XCD id (round-robin heuristic)
    const int r2 = blockIdx.x >> 3;
    const int kq = r2 & 3;
    const int tb = r2 >> 2;                    // 0..20  (6-row band)

    const int mt = wv >> 1;                    // 0..3 M-tile (16 uu each)
    const int ai = wv & 1;                     // a-pair half: a in {2ai, 2ai+1}

    const int kl = lane & 15;
    const int g4 = lane >> 4;

    f32x4 Yp[3][2][2];                          // [tt][p][q]
    #pragma unroll
    for (int t = 0; t < 3; ++t)
        #pragma unroll
        for (int p = 0; p < 2; ++p)
            #pragma unroll
            for (int q = 0; q < 2; ++q)
                Yp[t][p][q] = (f32x4){0.f, 0.f, 0.f, 0.f};

    // transform mapping: tm = uu tile (0..63), cg = c-group of 4 channels
    const int tm = lane;
    const int cg = wv;
    const bool tvalid = (tm < T_TILES);

    // A-fragment read base (within an ab plane)
    const int tmA   = mt * 16 + kl;
    const int abyte = tmA * VSTRIDE + g4 * 16;

    const short8* UfV = (const short8*)Uf;

    #pragma unroll
    for (int tt = 0; tt < 3; ++tt) {
        const int xrow0 = 6 * tb + 2 * tt;      // rows xrow0..xrow0+3 (max 127)
        #pragma unroll
        for (int ch = 0; ch < 2; ++ch) {
            // ---- transform: all 16 ab for 64 tm x 32 c' (4 channels/thread) ----
            #pragma unroll
            for (int hp = 0; hp < 2; ++hp) {    // c'-pair within this thread
                float vv[2][16];
                #pragma unroll
                for (int hh = 0; hh < 2; ++hh) {
                    #pragma unroll
                    for (int e = 0; e < 16; ++e) vv[hh][e] = 0.f;
                    if (tvalid) {
                        const int c = ch * 32 + cg * 4 + hp * 2 + hh;
                        const float* xp = x + (((size_t)(n * 64 + c)) * HW + xrow0) * HW + 2 * tm;
                        float d[4][4];
                        #pragma unroll
                        for (int rr = 0; rr < 4; ++rr) {
                            float2 lo = *reinterpret_cast<const float2*>(xp + rr * HW);
                            float2 hi = *reinterpret_cast<const float2*>(xp + rr * HW + 2);
                            d[rr][0] = lo.x; d[rr][1] = lo.y; d[rr][2] = hi.x; d[rr][3] = hi.y;
                        }
                        float w[4][4];
                        #pragma unroll
                        for (int j = 0; j < 4; ++j) {
                            w[0][j] = d[0][j] - d[2][j];
                            w[1][j] = d[1][j] + d[2][j];
                            w[2][j] = d[2][j] - d[1][j];
                            w[3][j] = d[1][j] - d[3][j];
                        }
                        #pragma unroll
                        for (int a = 0; a < 4; ++a) {
                            vv[hh][a*4+0] = w[a][0] - w[a][2];
                            vv[hh][a*4+1] = w[a][1] + w[a][2];
                            vv[hh][a*4+2] = w[a][2] - w[a][1];
                            vv[hh][a*4+3] = w[a][1] - w[a][3];
                        }
                    }
                }
                const int wb = tm * VSTRIDE + cg * 8 + hp * 4;
                #pragma unroll
                for (int ab = 0; ab < 16; ++ab)
                    *reinterpret_cast<unsigned int*>(smem + ab * VPLANE + wb) =
                        pkbf2(vv[0][ab], vv[1][ab]);
            }
            __syncthreads();

            // ---- GEMM: wave (mt, ai): a in {2ai, 2ai+1}, 4 b, 16 k ----
            f32x4 acc[2][4];
            #pragma unroll
            for (int aa = 0; aa < 2; ++aa)
                #pragma unroll
                for (int b = 0; b < 4; ++b)
                    acc[aa][b] = (f32x4){0.f, 0.f, 0.f, 0.f};

            #pragma unroll
            for (int aa = 0; aa < 2; ++aa) {
                const int a = 2 * ai + aa;
                #pragma unroll
                for (int b = 0; b < 4; ++b) {
                    const char* ap = smem + (a * 4 + b) * VPLANE + abyte;
                    uint2 q0 = *reinterpret_cast<const uint2*>(ap);
                    uint2 q1 = *reinterpret_cast<const uint2*>(ap + 8);
                    uint4 t; t.x = q0.x; t.y = q0.y; t.z = q1.x; t.w = q1.y;
                    short8 Af = *reinterpret_cast<short8*>(&t);
                    short8 Bf = UfV[(size_t)(((a * 4 + b) * 2 + ch) * 4 + kq) * 64 + lane];
                    acc[aa][b] = __builtin_amdgcn_mfma_f32_16x16x32_bf16(
                        Af, Bf, acc[aa][b], 0, 0, 0);
                }
            }

            // ---- fold (linear in partial sums) ----
            #pragma unroll
            for (int aa = 0; aa < 2; ++aa) {
                const int a = 2 * ai + aa;
                f32x4 t0 = acc[aa][0] + acc[aa][1] + acc[aa][2];
                f32x4 t1 = acc[aa][1] - acc[aa][2] - acc[aa][3];
                if (a == 0) { Yp[tt][0][0] += t0; Yp[tt][0][1] += t1; }
                if (a == 1) { Yp[tt][0][0] += t0; Yp[tt][0][1] += t1;
                              Yp[tt][1][0] += t0; Yp[tt][1][1] += t1; }
                if (a == 2) { Yp[tt][0][0] += t0; Yp[tt][0][1] += t1;
                              Yp[tt][1][0] -= t0; Yp[tt][1][1] -= t1; }
                if (a == 3) { Yp[tt][1][0] -= t0; Yp[tt][1][1] -= t1; }
            }
            __syncthreads();
        }
    }

    // ---- store: merge ai halves in LDS, then plane-contiguous float2 copy ----
    float* Ys = reinterpret_cast<float*>(smem);
    if (ai == 0) {
        #pragma unroll
        for (int tt = 0; tt < 3; ++tt)
            #pragma unroll
            for (int r = 0; r < 4; ++r) {
                const int uu = mt * 16 + 4 * g4 + r;
                if (uu < T_TILES) {
                    #pragma unroll
                    for (int p = 0; p < 2; ++p)
                        *reinterpret_cast<float2*>(Ys + kl * YSTRIDE + (2 * tt + p) * 126 + 2 * uu)
                            = make_float2(Yp[tt][p][0][r], Yp[tt][p][1][r]);
                }
            }
    }
    __syncthreads();
    if (ai == 1) {
        #pragma unroll
        for (int tt = 0; tt < 3; ++tt)
            #pragma unroll
            for (int r = 0; r < 4; ++r) {
                const int uu = mt * 16 + 4 * g4 + r;
                if (uu < T_TILES) {
                    #pragma unroll
                    for (int p = 0; p < 2; ++p) {
                        float2* ptr = reinterpret_cast<float2*>(
                            Ys + kl * YSTRIDE + (2 * tt + p) * 126 + 2 * uu);
                        float2 v = *ptr;
                        v.x += Yp[tt][p][0][r];
                        v.y += Yp[tt][p][1][r];
                        *ptr = v;
                    }
                }
            }
    }
    __syncthreads();

    // copy out: 16 planes x 756 floats (6 rows x 126) as float2
    const int kp = tid >> 5;                    // 0..15
    const int lx = tid & 31;
    const float* src = Ys + kp * YSTRIDE;
    float* dst = Y + ((size_t)(n * 64 + kq * 16 + kp)) * (OW * OW) + 756 * tb;
    #pragma unroll
    for (int it = 0; it < 12; ++it) {
        int idx = it * 32 + lx;
        if (idx < 378) {
            float2 v = *reinterpret_cast<const float2*>(src + 2 * idx);
            *reinterpret_cast<float2*>(dst + 2 * idx) = v;
        }
    }
}

extern "C" void kernel_launch(void* const* d_in, const int* in_sizes, int n_in,
                              void* d_out, int out_size, void* d_ws, size_t ws_size,
                              hipStream_t stream) {
    const float* x    = (const float*)d_in[0];
    const float* filt = (const float*)d_in[1];
    float* Y = (float*)d_out;
    unsigned short* Uf = (unsigned short*)d_ws;    // 128 KB bf16 U fragments

    filter_transform<<<16, 256, 0, stream>>>(filt, Uf);

    winograd_main<<<dim3(672), 512, 16 * VPLANE, stream>>>(x, Uf, Y);
}